// Round 1
// baseline (84.962 us; speedup 1.0000x reference)
//
#include <hip/hip_runtime.h>
#include <math.h>

#define NVIEW 3
#define HLOW 256
#define WLOW 256
#define NPIX (HLOW * WLOW)
#define NS 64
#define VOLN 128
#define IMGH 512
#define IMGW 512
#define BLK 256
#define BLOCKS_PER_VIEW (NPIX / BLK) // 256

// One thread per (view, low-res pixel). March 64 samples, online softmax for
// depth, accumulate occ partial sums, block-tree-reduce partials (deterministic).
__global__ __launch_bounds__(BLK) void raymarch_kernel(
    const float* __restrict__ intrs,    // [3,3,3]
    const float* __restrict__ c2ws,     // [3,4,4]
    const float* __restrict__ nearfars, // [3,2]
    const float* __restrict__ vol,      // [128,128,128] (D,H,W)
    float* __restrict__ depth_low,      // [3,256,256]
    float* __restrict__ partials)       // [3*256][3]
{
    const int view = blockIdx.x >> 8;                       // 256 blocks/view
    const int pix  = ((blockIdx.x & 255) << 8) + threadIdx.x;
    const int row  = pix >> 8;
    const int col  = pix & 255;

    // pixel grid: linspace(0, 511, 256) along each dim
    const float px = 511.0f * (float)col * (1.0f / 255.0f);
    const float py = 511.0f * (float)row * (1.0f / 255.0f);

    // analytic 3x3 inverse of intr (adjugate/det)
    const float* K = intrs + view * 9;
    const float a = K[0], b = K[1], c = K[2];
    const float d = K[3], e = K[4], f = K[5];
    const float g = K[6], h = K[7], i9 = K[8];
    const float det = a * (e * i9 - f * h) - b * (d * i9 - f * g) + c * (d * h - e * g);
    const float id = 1.0f / det;
    const float m00 = (e * i9 - f * h) * id, m01 = -(b * i9 - c * h) * id, m02 = (b * f - c * e) * id;
    const float m10 = -(d * i9 - f * g) * id, m11 = (a * i9 - c * g) * id, m12 = -(a * f - c * d) * id;
    const float m20 = (d * h - e * g) * id, m21 = -(a * h - b * g) * id, m22 = (a * e - b * d) * id;

    // cam = inv(intr) @ [px, py, 1]
    const float cx = m00 * px + m01 * py + m02;
    const float cy = m10 * px + m11 * py + m12;
    const float cz = m20 * px + m21 * py + m22;
    const float inr = rsqrtf(cx * cx + cy * cy + cz * cz);
    const float ncx = cx * inr, ncy = cy * inr, ncz = cz * inr;

    // world dir = R @ cam_n ; translation t
    const float* M = c2ws + view * 16;
    const float dx = M[0] * ncx + M[1] * ncy + M[2] * ncz;
    const float dy = M[4] * ncx + M[5] * ncy + M[6] * ncz;
    const float dz = M[8] * ncx + M[9] * ncy + M[10] * ncz;
    const float tx = M[3], ty = M[7], tz = M[11];

    const float nearv = nearfars[view * 2 + 0];
    const float farv  = nearfars[view * 2 + 1];
    const float zstep = (farv - nearv) * (1.0f / 63.0f);

    float mmax = -1e30f, lsum = 0.0f, zacc = 0.0f;
    float d6 = 0.0f, dout = 0.0f, cnt = 0.0f;

    for (int s = 0; s < NS; ++s) {
        const float z = nearv + zstep * (float)s;
        const float wxp = tx + dx * z;
        const float wyp = ty + dy * z;
        const float wzp = tz + dz * z;

        // trilinear sample, border clamp, align_corners=True
        float gx = (wxp + 1.0f) * 0.5f * 127.0f;
        float gy = (wyp + 1.0f) * 0.5f * 127.0f;
        float gz = (wzp + 1.0f) * 0.5f * 127.0f;
        gx = fminf(fmaxf(gx, 0.0f), 127.0f);
        gy = fminf(fmaxf(gy, 0.0f), 127.0f);
        gz = fminf(fmaxf(gz, 0.0f), 127.0f);
        const float x0f = floorf(gx), y0f = floorf(gy), z0f = floorf(gz);
        const float fx = gx - x0f, fy = gy - y0f, fz = gz - z0f;
        const int x0 = (int)x0f, y0 = (int)y0f, z0 = (int)z0f;
        const int x1 = min(x0 + 1, VOLN - 1);
        const int y1 = min(y0 + 1, VOLN - 1);
        const int z1 = min(z0 + 1, VOLN - 1);

        const float* p0 = vol + z0 * (VOLN * VOLN);
        const float* p1 = vol + z1 * (VOLN * VOLN);
        const int ry0 = y0 * VOLN, ry1 = y1 * VOLN;
        const float c000 = p0[ry0 + x0], c001 = p0[ry0 + x1];
        const float c010 = p0[ry1 + x0], c011 = p0[ry1 + x1];
        const float c100 = p1[ry0 + x0], c101 = p1[ry0 + x1];
        const float c110 = p1[ry1 + x0], c111 = p1[ry1 + x1];

        const float c00 = c000 * (1.0f - fx) + c001 * fx;
        const float c01 = c010 * (1.0f - fx) + c011 * fx;
        const float c10 = c100 * (1.0f - fx) + c101 * fx;
        const float c11 = c110 * (1.0f - fx) + c111 * fx;
        const float c0 = c00 * (1.0f - fy) + c01 * fy;
        const float c1 = c10 * (1.0f - fy) + c11 * fy;
        const float dens = c0 * (1.0f - fz) + c1 * fz;

        // online softmax accumulation for sum(exp) and sum(z*exp)
        if (dens > mmax) {
            const float sc = __expf(mmax - dens);
            lsum = lsum * sc + 1.0f;
            zacc = zacc * sc + z;
            mmax = dens;
        } else {
            const float w = __expf(dens - mmax);
            lsum += w;
            zacc += z * w;
        }

        if (s < 6) d6 += dens;
        const float r2 = wxp * wxp + wyp * wyp + wzp * wzp;
        if (r2 > 1.0f) { dout += dens; cnt += 1.0f; }
    }

    depth_low[view * NPIX + pix] = (zacc / lsum) * ncz;

    // deterministic block tree-reduction of the three occ partial sums
    __shared__ float s0[BLK], s1[BLK], s2[BLK];
    const int t = threadIdx.x;
    s0[t] = d6; s1[t] = dout; s2[t] = cnt;
    __syncthreads();
    for (int off = BLK / 2; off > 0; off >>= 1) {
        if (t < off) {
            s0[t] += s0[t + off];
            s1[t] += s1[t + off];
            s2[t] += s2[t + off];
        }
        __syncthreads();
    }
    if (t == 0) {
        partials[blockIdx.x * 3 + 0] = s0[0];
        partials[blockIdx.x * 3 + 1] = s1[0];
        partials[blockIdx.x * 3 + 2] = s2[0];
    }
}

// One block per view: reduce the 256 block-partials, write occ scalar.
__global__ __launch_bounds__(BLOCKS_PER_VIEW) void reduce_occ_kernel(
    const float* __restrict__ partials, float* __restrict__ out_occ)
{
    const int view = blockIdx.x;
    const int t = threadIdx.x;
    __shared__ float s0[BLOCKS_PER_VIEW], s1[BLOCKS_PER_VIEW], s2[BLOCKS_PER_VIEW];
    const int bi = view * BLOCKS_PER_VIEW + t;
    s0[t] = partials[bi * 3 + 0];
    s1[t] = partials[bi * 3 + 1];
    s2[t] = partials[bi * 3 + 2];
    __syncthreads();
    for (int off = BLOCKS_PER_VIEW / 2; off > 0; off >>= 1) {
        if (t < off) {
            s0[t] += s0[t + off];
            s1[t] += s1[t + off];
            s2[t] += s2[t + off];
        }
        __syncthreads();
    }
    if (t == 0) {
        out_occ[view] = s0[0] * (1.0f / (float)(NPIX * 6))
                      + s1[0] / (s2[0] + 1e-10f);
    }
}

// 256x256 -> 512x512 bilinear, jax.image.resize semantics:
// src = (i + 0.5) * 0.5 - 0.5; edge renormalization == index clamp.
__global__ __launch_bounds__(BLK) void upsample_kernel(
    const float* __restrict__ low, float* __restrict__ out)
{
    const int idx = blockIdx.x * BLK + threadIdx.x;
    const int view = idx / (IMGH * IMGW);
    const int rem = idx - view * (IMGH * IMGW);
    const int r = rem >> 9;
    const int cc = rem & 511;

    const float sy = (float)r * 0.5f - 0.25f;
    const float sx = (float)cc * 0.5f - 0.25f;
    const float y0f = floorf(sy), x0f = floorf(sx);
    const float wy = sy - y0f, wx = sx - x0f;
    const int y0 = (int)y0f, x0 = (int)x0f;
    const int y0c = max(y0, 0), y1c = min(y0 + 1, HLOW - 1);
    const int x0c = max(x0, 0), x1c = min(x0 + 1, WLOW - 1);

    const float* src = low + view * NPIX;
    const float v00 = src[y0c * WLOW + x0c];
    const float v01 = src[y0c * WLOW + x1c];
    const float v10 = src[y1c * WLOW + x0c];
    const float v11 = src[y1c * WLOW + x1c];

    const float top = v00 * (1.0f - wx) + v01 * wx;
    const float bot = v10 * (1.0f - wx) + v11 * wx;
    out[idx] = top * (1.0f - wy) + bot * wy;
}

extern "C" void kernel_launch(void* const* d_in, const int* in_sizes, int n_in,
                              void* d_out, int out_size, void* d_ws, size_t ws_size,
                              hipStream_t stream) {
    // input order: imgs, intrs, c2ws, near_fars, density_volume, stage_idx
    const float* intrs = (const float*)d_in[1];
    const float* c2ws  = (const float*)d_in[2];
    const float* nf    = (const float*)d_in[3];
    const float* vol   = (const float*)d_in[4];
    float* out = (float*)d_out;

    float* depth_low = (float*)d_ws;                    // 3*65536 floats
    float* partials  = depth_low + NVIEW * NPIX;        // 3*256*3 floats

    raymarch_kernel<<<NVIEW * BLOCKS_PER_VIEW, BLK, 0, stream>>>(
        intrs, c2ws, nf, vol, depth_low, partials);
    reduce_occ_kernel<<<NVIEW, BLOCKS_PER_VIEW, 0, stream>>>(
        partials, out + NVIEW * IMGH * IMGW);
    upsample_kernel<<<(NVIEW * IMGH * IMGW) / BLK, BLK, 0, stream>>>(
        depth_low, out);
}